// Round 22
// baseline (122.715 us; speedup 1.0000x reference)
//
#include <hip/hip_runtime.h>
#include <hip/hip_bf16.h>
#include <math.h>

#define BQ    4
#define LQ    2048
#define D_DIM 1024
#define NQ    2048
#define SMAX  1024
#define TOPK  8

typedef __attribute__((ext_vector_type(8))) short          short8;
typedef __attribute__((ext_vector_type(8))) _Float16       half8;
typedef __attribute__((ext_vector_type(4))) float          f32x4;
typedef __attribute__((ext_vector_type(8))) unsigned short ushort8;
typedef __attribute__((ext_vector_type(4))) unsigned short ushort4v;

typedef __attribute__((address_space(3))) void as3_void;
typedef __attribute__((address_space(1))) void as1_void;

__device__ __forceinline__ void gload_lds16(const void* g, void* l) {
    __builtin_amdgcn_global_load_lds((const as1_void*)g, (as3_void*)l, 16, 0, 0);
}

__device__ __forceinline__ unsigned short f2bf(float f) {
    __hip_bfloat16 h = __float2bfloat16(f);
    return *reinterpret_cast<unsigned short*>(&h);
}
__device__ __forceinline__ float bf2f(unsigned short u) {
    unsigned int w = (unsigned int)u << 16;
    return *reinterpret_cast<float*>(&w);
}
__device__ __forceinline__ unsigned short f2h(float f) {
    _Float16 h = (_Float16)f;
    return *reinterpret_cast<unsigned short*>(&h);
}
__device__ __forceinline__ float h2f(unsigned short u) {
    _Float16 h = *reinterpret_cast<_Float16*>(&u);
    return (float)h;
}

// slot-XOR swizzle: conflict-free within each 8-consecutive-lane b128 group.
__device__ __forceinline__ int swz(int r) { return (r ^ (r >> 2)) & 3; }

#define WAIT_VM0   asm volatile("s_waitcnt vmcnt(0)" ::: "memory")
#define WAIT_VM4   asm volatile("s_waitcnt vmcnt(4)" ::: "memory")
#define WAIT_VM6   asm volatile("s_waitcnt vmcnt(6)" ::: "memory")
#define WAIT_LGKM0 asm volatile("s_waitcnt lgkmcnt(0)" ::: "memory")

// ---------------------------------------------------------------------------
// Conversions + qptrs + Wg transpose. Token NOT pre-converted.
// Regions (2048 elems/block): [0,1024) desc fp16 hi/lo | [1024,1536) Wd fp16 |
// [1536,2048) out_w bf16 | [2048,3072) Z bf16 | [3072,3328) Wg^T fp16
__global__ __launch_bounds__(256) void k_cvt_all(
    const float* __restrict__ desc_q, const float* __restrict__ Wd_w,
    const float* __restrict__ out_w, const float* __restrict__ Z_sets,
    const float* __restrict__ Wg_w, const int* __restrict__ q_raw,
    unsigned short* __restrict__ descH, unsigned short* __restrict__ descL,
    unsigned short* __restrict__ wdh,   unsigned short* __restrict__ owb,
    unsigned short* __restrict__ Zb,    unsigned short* __restrict__ wgT,
    int* __restrict__ qp)
{
    __shared__ float t[64][65];
    const int blk = blockIdx.x;
    const int tid = threadIdx.x;

    if (blk == 0 && tid == 0) {
        bool is64 = (q_raw[1] == 0);
        for (int i = 0; i <= BQ; ++i)
            qp[i] = is64 ? q_raw[2 * i] : q_raw[i];
    }

    if (blk >= 3072) {
        const int tb = blk - 3072;
        const int j0 = (tb & 15) * 64;
        const int d0 = (tb >> 4) * 64;
#pragma unroll
        for (int i = 0; i < 16; ++i) {
            int r = i * 4 + (tid >> 6);
            int c = tid & 63;
            t[r][c] = Wg_w[(size_t)(d0 + r) * D_DIM + j0 + c];
        }
        __syncthreads();
#pragma unroll
        for (int i = 0; i < 16; ++i) {
            int jj = i * 4 + (tid >> 6);
            int dd = tid & 63;
            wgT[(size_t)(j0 + jj) * D_DIM + d0 + dd] = f2h(t[dd][jj]);
        }
        return;
    }

    const float* in; unsigned short *hi, *lo = nullptr; int local; bool fp16m = true;
    if (blk < 1024)      { in = desc_q; hi = descH; lo = descL; local = blk; }
    else if (blk < 1536) { in = Wd_w;   hi = wdh;   local = blk - 1024; }
    else if (blk < 2048) { in = out_w;  hi = owb;   local = blk - 1536; fp16m = false; }
    else                 { in = Z_sets; hi = Zb;    local = blk - 2048; fp16m = false; }

    int i = (local * 256 + tid) * 8;
    float4 v0 = *reinterpret_cast<const float4*>(in + i);
    float4 v1 = *reinterpret_cast<const float4*>(in + i + 4);
    float x[8] = {v0.x, v0.y, v0.z, v0.w, v1.x, v1.y, v1.z, v1.w};
    ushort8 h8, l8;
#pragma unroll
    for (int k = 0; k < 8; ++k) {
        if (fp16m) {
            unsigned short h = f2h(x[k]);
            h8[k] = h;
            l8[k] = f2h(x[k] - h2f(h));
        } else {
            h8[k] = f2bf(x[k]);
        }
    }
    *reinterpret_cast<ushort8*>(hi + i) = h8;
    if (lo) *reinterpret_cast<ushort8*>(lo + i) = l8;
}

// ---------------------------------------------------------------------------
// Merged Dproj (2-pass fp16-split, fp16 out) + ZW (plain bf16). 256 blocks.
__global__ __launch_bounds__(256) void k_dzw(
    const unsigned short* __restrict__ descH, const unsigned short* __restrict__ descL,
    const unsigned short* __restrict__ wdh,
    const float* __restrict__ Wd_b, unsigned short* __restrict__ Dproj16,
    const unsigned short* __restrict__ Zb, const unsigned short* __restrict__ owb,
    unsigned short* __restrict__ ZWb)
{
    constexpr int K = D_DIM, N = D_DIM;
    __shared__ __align__(16) char lds[2 * 24576];

    const int d = blockIdx.x;
    const int sub = d >> 1;
    const int bcol = (sub & 7) * 128;
    const int brow = (sub >> 3) * 128;

    const int tid = threadIdx.x;
    const int ln  = tid & 63;
    const int wid = tid >> 6;
    const int wm  = wid >> 1, wn = wid & 1;
    const int fr  = ln & 15, fs = ln >> 4;
    const int srow = tid >> 2;
    const int sslt = tid & 3;

    const int kk0 = (sslt ^ swz(srow)) << 3;
    const size_t offA0 = (size_t)(brow + srow) * K + kk0;
    const size_t offW0 = (size_t)(bcol + srow) * K + kk0;

    if ((d & 1) == 0) {
        auto stage = [&](char* base, int k0) {
            gload_lds16(descH + offA0 + k0,          base + wid * 1024);
            gload_lds16(descH + offA0 + 64 * K + k0, base + 4096 + wid * 1024);
            gload_lds16(descL + offA0 + k0,          base + 8192 + wid * 1024);
            gload_lds16(descL + offA0 + 64 * K + k0, base + 12288 + wid * 1024);
            gload_lds16(wdh + offW0 + k0,            base + 16384 + wid * 1024);
            gload_lds16(wdh + offW0 + 64 * K + k0,   base + 20480 + wid * 1024);
        };

        f32x4 acc[4][4] = {};
        stage(lds, 0);
        stage(lds + 24576, 32);

        const int NT = K / 32;
        for (int t = 0; t < NT; ++t) {
            if (t < NT - 1) { WAIT_VM6; } else { WAIT_VM0; }
            __builtin_amdgcn_s_barrier();

            char* base = lds + (t & 1) * 24576;
            half8 ahf[4], alf[4], bhf[4];
#pragma unroll
            for (int mi = 0; mi < 4; ++mi) {
                int r = wm * 64 + mi * 16 + fr;
                int o = r * 64 + ((fs ^ swz(r)) << 4);
                ahf[mi] = *reinterpret_cast<const half8*>(base + o);
                alf[mi] = *reinterpret_cast<const half8*>(base + 8192 + o);
            }
#pragma unroll
            for (int ni = 0; ni < 4; ++ni) {
                int c = wn * 64 + ni * 16 + fr;
                int o = c * 64 + ((fs ^ swz(c)) << 4);
                bhf[ni] = *reinterpret_cast<const half8*>(base + 16384 + o);
            }
            __builtin_amdgcn_s_setprio(1);
#pragma unroll
            for (int mi = 0; mi < 4; ++mi)
#pragma unroll
                for (int ni = 0; ni < 4; ++ni)
                    acc[mi][ni] = __builtin_amdgcn_mfma_f32_16x16x32_f16(
                        ahf[mi], bhf[ni], acc[mi][ni], 0, 0, 0);
#pragma unroll
            for (int mi = 0; mi < 4; ++mi)
#pragma unroll
                for (int ni = 0; ni < 4; ++ni)
                    acc[mi][ni] = __builtin_amdgcn_mfma_f32_16x16x32_f16(
                        alf[mi], bhf[ni], acc[mi][ni], 0, 0, 0);
            __builtin_amdgcn_s_setprio(0);

            WAIT_LGKM0;
            __builtin_amdgcn_s_barrier();
            if (t + 2 < NT) stage(base, (t + 2) * 32);
        }

        float bv[4];
#pragma unroll
        for (int ni = 0; ni < 4; ++ni)
            bv[ni] = Wd_b[bcol + wn * 64 + ni * 16 + fr];

#pragma unroll
        for (int mi = 0; mi < 4; ++mi) {
#pragma unroll
            for (int reg = 0; reg < 4; ++reg) {
                int row = brow + wm * 64 + mi * 16 + fs * 4 + reg;
#pragma unroll
                for (int ni = 0; ni < 4; ++ni) {
                    int col = bcol + wn * 64 + ni * 16 + fr;
                    Dproj16[(size_t)row * N + col] = f2h(acc[mi][ni][reg] + bv[ni]);
                }
            }
        }
    } else {
        auto stage = [&](char* base, int k0) {
            gload_lds16(Zb + offA0 + k0,           base + wid * 1024);
            gload_lds16(Zb + offA0 + 64 * K + k0,  base + 4096 + wid * 1024);
            gload_lds16(owb + offW0 + k0,          base + 8192 + wid * 1024);
            gload_lds16(owb + offW0 + 64 * K + k0, base + 12288 + wid * 1024);
        };

        f32x4 acc[4][4] = {};
        stage(lds, 0);
        stage(lds + 24576, 32);

        const int NT = K / 32;
        for (int t = 0; t < NT; ++t) {
            if (t < NT - 1) { WAIT_VM4; } else { WAIT_VM0; }
            __builtin_amdgcn_s_barrier();

            char* base = lds + (t & 1) * 24576;
            short8 a[4], b[4];
#pragma unroll
            for (int mi = 0; mi < 4; ++mi) {
                int r = wm * 64 + mi * 16 + fr;
                a[mi] = *reinterpret_cast<const short8*>(base + r * 64 + ((fs ^ swz(r)) << 4));
            }
#pragma unroll
            for (int ni = 0; ni < 4; ++ni) {
                int c = wn * 64 + ni * 16 + fr;
                b[ni] = *reinterpret_cast<const short8*>(base + 8192 + c * 64 + ((fs ^ swz(c)) << 4));
            }
            __builtin_amdgcn_s_setprio(1);
#pragma unroll
            for (int mi = 0; mi < 4; ++mi)
#pragma unroll
                for (int ni = 0; ni < 4; ++ni)
                    acc[mi][ni] = __builtin_amdgcn_mfma_f32_16x16x32_bf16(
                        a[mi], b[ni], acc[mi][ni], 0, 0, 0);
            __builtin_amdgcn_s_setprio(0);

            WAIT_LGKM0;
            __builtin_amdgcn_s_barrier();
            if (t + 2 < NT) stage(base, (t + 2) * 32);
        }

#pragma unroll
        for (int mi = 0; mi < 4; ++mi) {
#pragma unroll
            for (int reg = 0; reg < 4; ++reg) {
                int row = brow + wm * 64 + mi * 16 + fs * 4 + reg;
#pragma unroll
                for (int ni = 0; ni < 4; ++ni) {
                    int col = bcol + wn * 64 + ni * 16 + fr;
                    ZWb[(size_t)row * N + col] = f2bf(acc[mi][ni][reg]);
                }
            }
        }
    }
}

// ---------------------------------------------------------------------------
// Merged G-GEMM + cvec + tmap build. 640 blocks.
__global__ __launch_bounds__(256) void k_gc(
    const unsigned short* __restrict__ Dproj16, const unsigned short* __restrict__ wgT,
    unsigned short* __restrict__ G16,
    const float* __restrict__ bg, const int* __restrict__ qp,
    int* __restrict__ tmap, float* __restrict__ cvec)
{
    constexpr int K = D_DIM, N = D_DIM;
    __shared__ __align__(16) char lds[2 * 16384];

    const int blk = blockIdx.x;
    const int tid = threadIdx.x;

    if (blk >= 128) {
        if (blk == 128 && tid == 0) {
            int idx = 0;
            for (int b = 0; b < BQ; ++b) {
                int len = qp[b + 1] - qp[b];
                int nt = (len + 63) >> 6;
                for (int j = 0; j < nt; ++j)
                    tmap[idx++] = (b << 16) | (j * 64);
            }
            tmap[40] = idx;
        }
        const int row = (blk - 128) * 4 + (tid >> 6);
        const int ln  = tid & 63;
        const unsigned short* dr = Dproj16 + (size_t)row * D_DIM + ln * 16;
        float s = 0.f;
#pragma unroll
        for (int h = 0; h < 2; ++h) {
            ushort8 v = *reinterpret_cast<const ushort8*>(dr + h * 8);
#pragma unroll
            for (int j = 0; j < 8; ++j)
                s = fmaf(bg[ln * 16 + h * 8 + j], h2f(v[j]), s);
        }
#pragma unroll
        for (int off = 32; off > 0; off >>= 1)
            s += __shfl_xor(s, off);
        if (ln == 0) cvec[row] = s;
        return;
    }

    // ---- G tile ----
    const int logical = (blk & 7) * 16 + (blk >> 3);
    const int bcol = (logical & 7) * 128;
    const int brow = (logical >> 3) * 128;

    const int ln  = tid & 63;
    const int wid = tid >> 6;
    const int wm  = wid >> 1, wn = wid & 1;
    const int fr  = ln & 15, fs = ln >> 4;
    const int srow = tid >> 2;
    const int sslt = tid & 3;

    const int kk0 = (sslt ^ swz(srow)) << 3;
    const size_t offA0 = (size_t)(brow + srow) * K + kk0;
    const size_t offW0 = (size_t)(bcol + srow) * K + kk0;

    auto stage = [&](char* base, int k0) {
        gload_lds16(Dproj16 + offA0 + k0,          base + wid * 1024);
        gload_lds16(Dproj16 + offA0 + 64 * K + k0, base + 4096 + wid * 1024);
        gload_lds16(wgT + offW0 + k0,              base + 8192 + wid * 1024);
        gload_lds16(wgT + offW0 + 64 * K + k0,     base + 12288 + wid * 1024);
    };

    f32x4 acc[4][4] = {};

    stage(lds, 0);
    stage(lds + 16384, 32);

    const int NT = K / 32;
    for (int t = 0; t < NT; ++t) {
        if (t < NT - 1) { WAIT_VM4; } else { WAIT_VM0; }
        __builtin_amdgcn_s_barrier();

        char* base = lds + (t & 1) * 16384;
        half8 a[4], b[4];
#pragma unroll
        for (int mi = 0; mi < 4; ++mi) {
            int r = wm * 64 + mi * 16 + fr;
            a[mi] = *reinterpret_cast<const half8*>(base + r * 64 + ((fs ^ swz(r)) << 4));
        }
#pragma unroll
        for (int ni = 0; ni < 4; ++ni) {
            int c = wn * 64 + ni * 16 + fr;
            b[ni] = *reinterpret_cast<const half8*>(base + 8192 + c * 64 + ((fs ^ swz(c)) << 4));
        }
        __builtin_amdgcn_s_setprio(1);
#pragma unroll
        for (int mi = 0; mi < 4; ++mi)
#pragma unroll
            for (int ni = 0; ni < 4; ++ni)
                acc[mi][ni] = __builtin_amdgcn_mfma_f32_16x16x32_f16(
                    a[mi], b[ni], acc[mi][ni], 0, 0, 0);
        __builtin_amdgcn_s_setprio(0);

        WAIT_LGKM0;
        __builtin_amdgcn_s_barrier();
        if (t + 2 < NT) stage(base, (t + 2) * 32);
    }

#pragma unroll
    for (int mi = 0; mi < 4; ++mi) {
#pragma unroll
        for (int reg = 0; reg < 4; ++reg) {
            int row = brow + wm * 64 + mi * 16 + fs * 4 + reg;
#pragma unroll
            for (int ni = 0; ni < 4; ++ni) {
                int col = bcol + wn * 64 + ni * 16 + fr;
                G16[(size_t)row * N + col] = f2h(acc[mi][ni][reg]);
            }
        }
    }
}

// ---------------------------------------------------------------------------
// Windowed logits, BM=32 x BN=64, 128-thread blocks (2 waves), ~2176 live
// blocks = 8.5/CU -> ~17 waves/CU of TLP for the latency-bound chain.
// Token fp32 read directly + in-reg fp16 hi/lo split (bit-identical math);
// G via global_load_lds (2 per wave, issued FIRST). 2-deep pipeline,
// 2 barriers/iter. LDS: 2 x 8 KB {TH 2K | TL 2K | G 4K}.
__global__ __launch_bounds__(128) void k_logits32(
    const float* __restrict__ tok, const unsigned short* __restrict__ G16,
    const float* __restrict__ cvec, const int* __restrict__ qp,
    const int* __restrict__ tmap, float* __restrict__ logits)
{
    const int d = blockIdx.x + 40 * blockIdx.y;          // 0..2559
    const int logical = (d & 7) * 320 + (d >> 3);        // XCD-chunked bijection
    const int t0   = logical % 40;
    const int brow = (logical / 40) * 32;                // 64 l-tiles of 32
    if (t0 >= tmap[40]) return;                          // block-uniform
    const int m    = tmap[t0];
    const int b    = m >> 16;
    const int bcol = m & 0xffff;
    const int start = qp[b];

    __shared__ __align__(16) char lds[2 * 8192];

    const int tid = threadIdx.x;                         // 0..127
    const int ln  = tid & 63;
    const int wid = tid >> 6;                            // 0..1
    const int fr  = ln & 15, fs = ln >> 4;

    // token staging: thread owns group tid -> row = tid>>2 (0..31), slot = tid&3
    const int srow = tid >> 2;
    const int sslt = tid & 3;
    const int kka  = (sslt ^ swz(srow)) << 3;
    const size_t tokOff = ((size_t)b * LQ + brow + srow) * D_DIM + kka;
    const int ldsByte = srow * 64 + sslt * 16;           // TH/TL linear dest

    // G staging: per wave 2 gload_lds at bases wid*2048 (+1024); lane ln of
    // load j covers LDS slot s = wid*128 + j*64 + ln -> grow = s>>2, gslot = s&3
    size_t offG[2];
#pragma unroll
    for (int j = 0; j < 2; ++j) {
        int s = wid * 128 + j * 64 + ln;
        int grow = s >> 2, gslot = s & 3;
        int wr = start + bcol + grow; if (wr > NQ - 1) wr = NQ - 1;
        offG[j] = (size_t)wr * D_DIM + ((gslot ^ swz(grow)) << 3);
    }

    f32x4 acc[4] = {};

    // issue one tile's loads: G FIRST (2x gload_lds), then token fp32 to regs
    auto issueTile = [&](int k0, char* buf, float4& x0, float4& x1) {
        gload_lds16(G16 + offG[0] + k0, buf + 4096 + wid * 2048);
        gload_lds16(G16 + offG[1] + k0, buf + 4096 + wid * 2048 + 1024);
        x0 = *reinterpret_cast<const float4*>(tok + tokOff + k0);
        x1 = *reinterpret_cast<const float4*>(tok + tokOff + k0 + 4);
    };
    auto writeTile = [&](char* buf, float4 x0, float4 x1) {
        float xs[8] = {x0.x, x0.y, x0.z, x0.w, x1.x, x1.y, x1.z, x1.w};
        ushort8 h8, l8;
#pragma unroll
        for (int k = 0; k < 8; ++k) {
            unsigned short h = f2h(xs[k]);
            h8[k] = h;
            l8[k] = f2h(xs[k] - h2f(h));
        }
        *reinterpret_cast<ushort8*>(buf + ldsByte) = h8;
        *reinterpret_cast<ushort8*>(buf + 2048 + ldsByte) = l8;
    };
    auto compute = [&](char* buf) {
        half8 ah, al, bf[4];
        {
            int r = wid * 16 + fr;                       // 0..31
            int o = r * 64 + ((fs ^ swz(r)) << 4);
            ah = *reinterpret_cast<const half8*>(buf + o);
            al = *reinterpret_cast<const half8*>(buf + 2048 + o);
        }
#pragma unroll
        for (int ni = 0; ni < 4; ++ni) {
            int cc = ni * 16 + fr;                       // 0..63
            bf[ni] = *reinterpret_cast<const half8*>(buf + 4096 + cc * 64 + ((fs ^ swz(cc)) << 4));
        }
        __builtin_amdgcn_s_setprio(1);
#pragma unroll
        for (int ni = 0; ni < 4; ++ni)
            acc[ni] = __builtin_amdgcn_mfma_f32_16x16x32_f16(ah, bf[ni], acc[ni], 0, 0, 0);
#pragma unroll
        for (int ni = 0; ni < 4; ++ni)
            acc[ni] = __builtin_amdgcn_mfma_f32_16x16x32_f16(al, bf[ni], acc[ni], 0, 0, 0);
        __builtin_amdgcn_s_setprio(0);
    };

    float4 a0, a1, b0, b1;                       // two in-flight tiles (named: rule #20)
    issueTile(0,  lds, a0, a1);
    issueTile(32, lds + 8192, b0, b1);

    const int NT = D_DIM / 32;                   // 32 (even)
    for (int tt = 0; tt < NT / 2; ++tt) {
        {   // even tile t = 2*tt, buffer 0
            int t = 2 * tt;
            if (t < NT - 1) { WAIT_VM4; } else { WAIT_VM0; }
            writeTile(lds, a0, a1);
            WAIT_LGKM0;
            __builtin_amdgcn_s_barrier();
            compute(lds);
            __builtin_amdgcn_s_barrier();
            if (t + 2 < NT) issueTile((t + 2) * 32, lds, a0, a1);
        }
        {   // odd tile t = 2*tt+1, buffer 1
            int t = 2 * tt + 1;
            if (t < NT - 1) { WAIT_VM4; } else { WAIT_VM0; }
            writeTile(lds + 8192, b0, b1);
            WAIT_LGKM0;
            __builtin_amdgcn_s_barrier();
            compute(lds + 8192);
            __builtin_amdgcn_s_barrier();
            if (t + 2 < NT) issueTile((t + 2) * 32, lds + 8192, b0, b1);
        }
    }

    float cv[4];
#pragma unroll
    for (int ni = 0; ni < 4; ++ni) {
        int ci = start + bcol + ni * 16 + fr;
        if (ci > NQ - 1) ci = NQ - 1;
        cv[ni] = cvec[ci];
    }

#pragma unroll
    for (int reg = 0; reg < 4; ++reg) {
        size_t row = (size_t)b * LQ + brow + wid * 16 + fs * 4 + reg;
#pragma unroll
        for (int ni = 0; ni < 4; ++ni) {
            int col = bcol + ni * 16 + fr;
            logits[row * SMAX + col] = acc[ni][reg] + cv[ni];
        }
    }
}

// ---------------------------------------------------------------------------
// Wave-per-row top-8 + softmax + ZW gather + out_b -> final fp32 output.
__global__ __launch_bounds__(256) void k_topk_out(
    const float* __restrict__ logits, const unsigned short* __restrict__ ZW,
    const float* __restrict__ out_b, const int* __restrict__ qp,
    float* __restrict__ out)
{
    const int ln  = threadIdx.x & 63;
    const int row = blockIdx.x * 4 + (threadIdx.x >> 6);   // (b*L + l)
    const int b   = row >> 11;                              // L = 2048
    const int start = qp[b], len = qp[b + 1] - start;

    const float* lrow = logits + (size_t)row * SMAX;

    float v[16];
#pragma unroll
    for (int c = 0; c < 4; ++c) {
        float4 q = reinterpret_cast<const float4*>(lrow)[c * 64 + ln];
        int s0 = c * 256 + ln * 4;
        v[c * 4 + 0] = (s0 + 0 < len) ? q.x : -INFINITY;
        v[c * 4 + 1] = (s0 + 1 < len) ? q.y : -INFINITY;
        v[c * 4 + 2] = (s0 + 2 < len) ? q.z : -INFINITY;
        v[c * 4 + 3] = (s0 + 3 < len) ? q.w : -INFINITY;
    }

    float wv[TOPK]; int wi[TOPK];
#pragma unroll
    for (int it = 0; it < TOPK; ++it) {
        float bvv = v[0]; int bj = 0;
#pragma unroll
        for (int j = 1; j < 16; ++j)
            if (v[j] > bvv) { bvv = v[j]; bj = j; }
        int gidx = (bj >> 2) * 256 + ln * 4 + (bj & 3);
        float cv = bvv; int ci = gidx;
#pragma unroll
        for (int off = 32; off > 0; off >>= 1) {
            float ov = __shfl_xor(cv, off);
            int   oi = __shfl_xor(ci, off);
            if (ov > cv || (ov == cv && oi < ci)) { cv = ov; ci = oi; }
        }
        wv[it] = cv; wi[it] = ci;
#pragma unroll
        for (int j = 0; j < 16; ++j) {
            int sj = (j >> 2) * 256 + ln * 4 + (j & 3);
            if (sj == ci) v[j] = -INFINITY;
        }
    }

    float m = wv[0], denom = 0.f;
    float g[TOPK];
#pragma unroll
    for (int k = 0; k < TOPK; ++k) { g[k] = expf(wv[k] - m); denom += g[k]; }
    float inv = 1.f / denom;

    float4 acc[4];
#pragma unroll
    for (int c = 0; c < 4; ++c)
        acc[c] = reinterpret_cast<const float4*>(out_b)[c * 64 + ln];

#pragma unroll
    for (int k = 0; k < TOPK; ++k) {
        int si = wi[k] >= 0 ? wi[k] : 0;
        const ushort4v* zr = reinterpret_cast<const ushort4v*>(
            ZW + (size_t)(start + si) * D_DIM);
        float wgt = g[k] * inv;
#pragma unroll
        for (int c = 0; c < 4; ++c) {
            ushort4v z = zr[c * 64 + ln];
            acc[c].x = fmaf(wgt, bf2f(z[0]), acc[c].x);
            acc[c].y = fmaf(wgt, bf2f(z[1]), acc[c].y);
            acc[c].z = fmaf(wgt, bf2f(z[2]), acc[c].z);
            acc[c].w = fmaf(wgt, bf2f(z[3]), acc[c].w);
        }
    }
    float* orow = out + (size_t)row * D_DIM;
#pragma unroll
    for (int c = 0; c < 4; ++c)
        reinterpret_cast<float4*>(orow)[c * 64 + ln] = acc[c];
}

// ---------------------------------------------------------------------------
extern "C" void kernel_launch(void* const* d_in, const int* in_sizes, int n_in,
                              void* d_out, int out_size, void* d_ws, size_t ws_size,
                              hipStream_t stream) {
    const float* token_states = (const float*)d_in[0];
    const float* Z_sets       = (const float*)d_in[1];
    const float* desc_q       = (const float*)d_in[2];
    const int*   q_raw        = (const int*)d_in[3];
    const float* Wg_w  = (const float*)d_in[4];
    const float* Wg_b  = (const float*)d_in[5];
    const float* Wd_w  = (const float*)d_in[6];
    const float* Wd_b  = (const float*)d_in[7];
    const float* out_w = (const float*)d_in[8];
    const float* out_b = (const float*)d_in[9];
    float* out = (float*)d_out;

    const size_t NDES = (size_t)NQ * D_DIM;        // 2097152
    const size_t NW   = (size_t)D_DIM * D_DIM;     // 1048576

    char* ws = (char*)d_ws;
    int* qp   = (int*)ws;                                    // [0,64)
    int* tmap = (int*)(ws + 64);                             // [64,256)
    unsigned short* descH   = (unsigned short*)(ws + 256);   // fp16 [2048][1024]
    unsigned short* descL   = descH + NDES;                  // fp16
    unsigned short* wdh     = descL + NDES;                  // fp16
    unsigned short* wgT     = wdh + NW;                      // fp16 (Wg^T)
    unsigned short* owb     = wgT + NW;                      // bf16
    unsigned short* Zb      = owb + NW;                      // bf16
    unsigned short* Dproj16 = Zb + NDES;                     // fp16 [2048][1024]
    unsigned short* ZWb     = Dproj16 + NDES;                // bf16 [2048][1024]
    unsigned short* G16     = ZWb + NDES;                    // fp16 [2048][1024]
    float* cvec             = (float*)(G16 + NDES);          // fp32 [2048]
    float* logit            = cvec + 2048;                   // fp32 [8192][1024]

    // conversions + qptrs + Wg transpose (token not pre-converted)
    k_cvt_all<<<3328, 256, 0, stream>>>(
        desc_q, Wd_w, out_w, Z_sets, Wg_w, q_raw,
        descH, descL, wdh, owb, Zb, wgT, qp);

    // Dproj (2-pass fp16-split) + ZW (bf16): 256 blocks
    k_dzw<<<256, 256, 0, stream>>>(
        descH, descL, wdh, Wd_b, Dproj16, Zb, owb, ZWb);

    // G = Dproj @ Wg + cvec + tmap: 640 blocks co-run
    k_gc<<<640, 256, 0, stream>>>(
        Dproj16, wgT, G16, Wg_b, qp, tmap, cvec);

    // logits = token(fp32, in-reg split) @ G^T + c: BM=32, grid (40,64), 128 thr
    k_logits32<<<dim3(40, 64), 128, 0, stream>>>(
        token_states, G16, cvec, qp, tmap, logit);

    // top-8 + softmax + ZW gather + bias -> final output
    k_topk_out<<<(BQ * LQ) / 4, 256, 0, stream>>>(logit, ZWb, out_b, qp, out);
}

// Round 23
// 119.351 us; speedup vs baseline: 1.0282x; 1.0282x over previous
//
#include <hip/hip_runtime.h>
#include <hip/hip_bf16.h>
#include <math.h>

#define BQ    4
#define LQ    2048
#define D_DIM 1024
#define NQ    2048
#define SMAX  1024
#define TOPK  8

typedef __attribute__((ext_vector_type(8))) short          short8;
typedef __attribute__((ext_vector_type(8))) _Float16       half8;
typedef __attribute__((ext_vector_type(4))) float          f32x4;
typedef __attribute__((ext_vector_type(8))) unsigned short ushort8;
typedef __attribute__((ext_vector_type(4))) unsigned short ushort4v;

typedef __attribute__((address_space(3))) void as3_void;
typedef __attribute__((address_space(1))) void as1_void;

__device__ __forceinline__ void gload_lds16(const void* g, void* l) {
    __builtin_amdgcn_global_load_lds((const as1_void*)g, (as3_void*)l, 16, 0, 0);
}

__device__ __forceinline__ unsigned short f2bf(float f) {
    __hip_bfloat16 h = __float2bfloat16(f);
    return *reinterpret_cast<unsigned short*>(&h);
}
__device__ __forceinline__ float bf2f(unsigned short u) {
    unsigned int w = (unsigned int)u << 16;
    return *reinterpret_cast<float*>(&w);
}
__device__ __forceinline__ unsigned short f2h(float f) {
    _Float16 h = (_Float16)f;
    return *reinterpret_cast<unsigned short*>(&h);
}
__device__ __forceinline__ float h2f(unsigned short u) {
    _Float16 h = *reinterpret_cast<_Float16*>(&u);
    return (float)h;
}

// slot-XOR swizzle: conflict-free within each 8-consecutive-lane b128 group.
__device__ __forceinline__ int swz(int r) { return (r ^ (r >> 2)) & 3; }

#define WAIT_VM0   asm volatile("s_waitcnt vmcnt(0)" ::: "memory")
#define WAIT_VM3   asm volatile("s_waitcnt vmcnt(3)" ::: "memory")
#define WAIT_VM4   asm volatile("s_waitcnt vmcnt(4)" ::: "memory")
#define WAIT_VM6   asm volatile("s_waitcnt vmcnt(6)" ::: "memory")
#define WAIT_LGKM0 asm volatile("s_waitcnt lgkmcnt(0)" ::: "memory")

// ---------------------------------------------------------------------------
// Conversions + qptrs + Wg transpose. Token is NOT pre-converted
// (logits converts in-kernel). Regions (2048 elems/block):
// [0,1024) desc -> fp16 hi/lo | [1024,1536) Wd -> fp16 |
// [1536,2048) out_w -> bf16 | [2048,3072) Z -> bf16 |
// [3072,3328) Wg 64x64 transpose tiles -> wgT fp16
__global__ __launch_bounds__(256) void k_cvt_all(
    const float* __restrict__ desc_q, const float* __restrict__ Wd_w,
    const float* __restrict__ out_w, const float* __restrict__ Z_sets,
    const float* __restrict__ Wg_w, const int* __restrict__ q_raw,
    unsigned short* __restrict__ descH, unsigned short* __restrict__ descL,
    unsigned short* __restrict__ wdh,   unsigned short* __restrict__ owb,
    unsigned short* __restrict__ Zb,    unsigned short* __restrict__ wgT,
    int* __restrict__ qp)
{
    __shared__ float t[64][65];
    const int blk = blockIdx.x;
    const int tid = threadIdx.x;

    if (blk == 0 && tid == 0) {
        bool is64 = (q_raw[1] == 0);
        for (int i = 0; i <= BQ; ++i)
            qp[i] = is64 ? q_raw[2 * i] : q_raw[i];
    }

    if (blk >= 3072) {
        // Wg transpose tile: wgT[j][d] = Wg[d][j] (fp16)
        const int tb = blk - 3072;
        const int j0 = (tb & 15) * 64;
        const int d0 = (tb >> 4) * 64;
#pragma unroll
        for (int i = 0; i < 16; ++i) {
            int r = i * 4 + (tid >> 6);
            int c = tid & 63;
            t[r][c] = Wg_w[(size_t)(d0 + r) * D_DIM + j0 + c];
        }
        __syncthreads();
#pragma unroll
        for (int i = 0; i < 16; ++i) {
            int jj = i * 4 + (tid >> 6);
            int dd = tid & 63;
            wgT[(size_t)(j0 + jj) * D_DIM + d0 + dd] = f2h(t[dd][jj]);
        }
        return;
    }

    const float* in; unsigned short *hi, *lo = nullptr; int local; bool fp16m = true;
    if (blk < 1024)      { in = desc_q; hi = descH; lo = descL; local = blk; }
    else if (blk < 1536) { in = Wd_w;   hi = wdh;   local = blk - 1024; }
    else if (blk < 2048) { in = out_w;  hi = owb;   local = blk - 1536; fp16m = false; }
    else                 { in = Z_sets; hi = Zb;    local = blk - 2048; fp16m = false; }

    int i = (local * 256 + tid) * 8;
    float4 v0 = *reinterpret_cast<const float4*>(in + i);
    float4 v1 = *reinterpret_cast<const float4*>(in + i + 4);
    float x[8] = {v0.x, v0.y, v0.z, v0.w, v1.x, v1.y, v1.z, v1.w};
    ushort8 h8, l8;
#pragma unroll
    for (int k = 0; k < 8; ++k) {
        if (fp16m) {
            unsigned short h = f2h(x[k]);
            h8[k] = h;
            l8[k] = f2h(x[k] - h2f(h));
        } else {
            h8[k] = f2bf(x[k]);
        }
    }
    *reinterpret_cast<ushort8*>(hi + i) = h8;
    if (lo) *reinterpret_cast<ushort8*>(lo + i) = l8;
}

// ---------------------------------------------------------------------------
// Merged Dproj (2-pass fp16-split, fp16 out) + ZW (plain bf16). 256 blocks.
__global__ __launch_bounds__(256) void k_dzw(
    const unsigned short* __restrict__ descH, const unsigned short* __restrict__ descL,
    const unsigned short* __restrict__ wdh,
    const float* __restrict__ Wd_b, unsigned short* __restrict__ Dproj16,
    const unsigned short* __restrict__ Zb, const unsigned short* __restrict__ owb,
    unsigned short* __restrict__ ZWb)
{
    constexpr int K = D_DIM, N = D_DIM;
    __shared__ __align__(16) char lds[2 * 24576];

    const int d = blockIdx.x;
    const int sub = d >> 1;
    const int bcol = (sub & 7) * 128;
    const int brow = (sub >> 3) * 128;

    const int tid = threadIdx.x;
    const int ln  = tid & 63;
    const int wid = tid >> 6;
    const int wm  = wid >> 1, wn = wid & 1;
    const int fr  = ln & 15, fs = ln >> 4;
    const int srow = tid >> 2;
    const int sslt = tid & 3;

    const int kk0 = (sslt ^ swz(srow)) << 3;
    const size_t offA0 = (size_t)(brow + srow) * K + kk0;
    const size_t offW0 = (size_t)(bcol + srow) * K + kk0;

    if ((d & 1) == 0) {
        auto stage = [&](char* base, int k0) {
            gload_lds16(descH + offA0 + k0,          base + wid * 1024);
            gload_lds16(descH + offA0 + 64 * K + k0, base + 4096 + wid * 1024);
            gload_lds16(descL + offA0 + k0,          base + 8192 + wid * 1024);
            gload_lds16(descL + offA0 + 64 * K + k0, base + 12288 + wid * 1024);
            gload_lds16(wdh + offW0 + k0,            base + 16384 + wid * 1024);
            gload_lds16(wdh + offW0 + 64 * K + k0,   base + 20480 + wid * 1024);
        };

        f32x4 acc[4][4] = {};
        stage(lds, 0);
        stage(lds + 24576, 32);

        const int NT = K / 32;
        for (int t = 0; t < NT; ++t) {
            if (t < NT - 1) { WAIT_VM6; } else { WAIT_VM0; }
            __builtin_amdgcn_s_barrier();

            char* base = lds + (t & 1) * 24576;
            half8 ahf[4], alf[4], bhf[4];
#pragma unroll
            for (int mi = 0; mi < 4; ++mi) {
                int r = wm * 64 + mi * 16 + fr;
                int o = r * 64 + ((fs ^ swz(r)) << 4);
                ahf[mi] = *reinterpret_cast<const half8*>(base + o);
                alf[mi] = *reinterpret_cast<const half8*>(base + 8192 + o);
            }
#pragma unroll
            for (int ni = 0; ni < 4; ++ni) {
                int c = wn * 64 + ni * 16 + fr;
                int o = c * 64 + ((fs ^ swz(c)) << 4);
                bhf[ni] = *reinterpret_cast<const half8*>(base + 16384 + o);
            }
            __builtin_amdgcn_s_setprio(1);
#pragma unroll
            for (int mi = 0; mi < 4; ++mi)
#pragma unroll
                for (int ni = 0; ni < 4; ++ni)
                    acc[mi][ni] = __builtin_amdgcn_mfma_f32_16x16x32_f16(
                        ahf[mi], bhf[ni], acc[mi][ni], 0, 0, 0);
#pragma unroll
            for (int mi = 0; mi < 4; ++mi)
#pragma unroll
                for (int ni = 0; ni < 4; ++ni)
                    acc[mi][ni] = __builtin_amdgcn_mfma_f32_16x16x32_f16(
                        alf[mi], bhf[ni], acc[mi][ni], 0, 0, 0);
            __builtin_amdgcn_s_setprio(0);

            WAIT_LGKM0;
            __builtin_amdgcn_s_barrier();
            if (t + 2 < NT) stage(base, (t + 2) * 32);
        }

        float bv[4];
#pragma unroll
        for (int ni = 0; ni < 4; ++ni)
            bv[ni] = Wd_b[bcol + wn * 64 + ni * 16 + fr];

#pragma unroll
        for (int mi = 0; mi < 4; ++mi) {
#pragma unroll
            for (int reg = 0; reg < 4; ++reg) {
                int row = brow + wm * 64 + mi * 16 + fs * 4 + reg;
#pragma unroll
                for (int ni = 0; ni < 4; ++ni) {
                    int col = bcol + wn * 64 + ni * 16 + fr;
                    Dproj16[(size_t)row * N + col] = f2h(acc[mi][ni][reg] + bv[ni]);
                }
            }
        }
    } else {
        auto stage = [&](char* base, int k0) {
            gload_lds16(Zb + offA0 + k0,           base + wid * 1024);
            gload_lds16(Zb + offA0 + 64 * K + k0,  base + 4096 + wid * 1024);
            gload_lds16(owb + offW0 + k0,          base + 8192 + wid * 1024);
            gload_lds16(owb + offW0 + 64 * K + k0, base + 12288 + wid * 1024);
        };

        f32x4 acc[4][4] = {};
        stage(lds, 0);
        stage(lds + 24576, 32);

        const int NT = K / 32;
        for (int t = 0; t < NT; ++t) {
            if (t < NT - 1) { WAIT_VM4; } else { WAIT_VM0; }
            __builtin_amdgcn_s_barrier();

            char* base = lds + (t & 1) * 24576;
            short8 a[4], b[4];
#pragma unroll
            for (int mi = 0; mi < 4; ++mi) {
                int r = wm * 64 + mi * 16 + fr;
                a[mi] = *reinterpret_cast<const short8*>(base + r * 64 + ((fs ^ swz(r)) << 4));
            }
#pragma unroll
            for (int ni = 0; ni < 4; ++ni) {
                int c = wn * 64 + ni * 16 + fr;
                b[ni] = *reinterpret_cast<const short8*>(base + 8192 + c * 64 + ((fs ^ swz(c)) << 4));
            }
            __builtin_amdgcn_s_setprio(1);
#pragma unroll
            for (int mi = 0; mi < 4; ++mi)
#pragma unroll
                for (int ni = 0; ni < 4; ++ni)
                    acc[mi][ni] = __builtin_amdgcn_mfma_f32_16x16x32_bf16(
                        a[mi], b[ni], acc[mi][ni], 0, 0, 0);
            __builtin_amdgcn_s_setprio(0);

            WAIT_LGKM0;
            __builtin_amdgcn_s_barrier();
            if (t + 2 < NT) stage(base, (t + 2) * 32);
        }

#pragma unroll
        for (int mi = 0; mi < 4; ++mi) {
#pragma unroll
            for (int reg = 0; reg < 4; ++reg) {
                int row = brow + wm * 64 + mi * 16 + fs * 4 + reg;
#pragma unroll
                for (int ni = 0; ni < 4; ++ni) {
                    int col = bcol + wn * 64 + ni * 16 + fr;
                    ZWb[(size_t)row * N + col] = f2bf(acc[mi][ni][reg]);
                }
            }
        }
    }
}

// ---------------------------------------------------------------------------
// Merged G-GEMM + cvec + tmap build. 640 blocks:
//   [0,128)   : G = Dproj @ Wg tile (single-pass fp16, 128x128)
//   [128,640) : cvec rows (4/block); block 128 also builds tmap.
__global__ __launch_bounds__(256) void k_gc(
    const unsigned short* __restrict__ Dproj16, const unsigned short* __restrict__ wgT,
    unsigned short* __restrict__ G16,
    const float* __restrict__ bg, const int* __restrict__ qp,
    int* __restrict__ tmap, float* __restrict__ cvec)
{
    constexpr int K = D_DIM, N = D_DIM;
    __shared__ __align__(16) char lds[2 * 16384];

    const int blk = blockIdx.x;
    const int tid = threadIdx.x;

    if (blk >= 128) {
        if (blk == 128 && tid == 0) {
            int idx = 0;
            for (int b = 0; b < BQ; ++b) {
                int len = qp[b + 1] - qp[b];
                int nt = (len + 63) >> 6;
                for (int j = 0; j < nt; ++j)
                    tmap[idx++] = (b << 16) | (j * 64);
            }
            tmap[40] = idx;
        }
        const int row = (blk - 128) * 4 + (tid >> 6);
        const int ln  = tid & 63;
        const unsigned short* dr = Dproj16 + (size_t)row * D_DIM + ln * 16;
        float s = 0.f;
#pragma unroll
        for (int h = 0; h < 2; ++h) {
            ushort8 v = *reinterpret_cast<const ushort8*>(dr + h * 8);
#pragma unroll
            for (int j = 0; j < 8; ++j)
                s = fmaf(bg[ln * 16 + h * 8 + j], h2f(v[j]), s);
        }
#pragma unroll
        for (int off = 32; off > 0; off >>= 1)
            s += __shfl_xor(s, off);
        if (ln == 0) cvec[row] = s;
        return;
    }

    // ---- G tile ----
    const int logical = (blk & 7) * 16 + (blk >> 3);
    const int bcol = (logical & 7) * 128;
    const int brow = (logical >> 3) * 128;

    const int ln  = tid & 63;
    const int wid = tid >> 6;
    const int wm  = wid >> 1, wn = wid & 1;
    const int fr  = ln & 15, fs = ln >> 4;
    const int srow = tid >> 2;
    const int sslt = tid & 3;

    const int kk0 = (sslt ^ swz(srow)) << 3;
    const size_t offA0 = (size_t)(brow + srow) * K + kk0;
    const size_t offW0 = (size_t)(bcol + srow) * K + kk0;

    auto stage = [&](char* base, int k0) {
        gload_lds16(Dproj16 + offA0 + k0,          base + wid * 1024);
        gload_lds16(Dproj16 + offA0 + 64 * K + k0, base + 4096 + wid * 1024);
        gload_lds16(wgT + offW0 + k0,              base + 8192 + wid * 1024);
        gload_lds16(wgT + offW0 + 64 * K + k0,     base + 12288 + wid * 1024);
    };

    f32x4 acc[4][4] = {};

    stage(lds, 0);
    stage(lds + 16384, 32);

    const int NT = K / 32;
    for (int t = 0; t < NT; ++t) {
        if (t < NT - 1) { WAIT_VM4; } else { WAIT_VM0; }
        __builtin_amdgcn_s_barrier();

        char* base = lds + (t & 1) * 16384;
        half8 a[4], b[4];
#pragma unroll
        for (int mi = 0; mi < 4; ++mi) {
            int r = wm * 64 + mi * 16 + fr;
            a[mi] = *reinterpret_cast<const half8*>(base + r * 64 + ((fs ^ swz(r)) << 4));
        }
#pragma unroll
        for (int ni = 0; ni < 4; ++ni) {
            int c = wn * 64 + ni * 16 + fr;
            b[ni] = *reinterpret_cast<const half8*>(base + 8192 + c * 64 + ((fs ^ swz(c)) << 4));
        }
        __builtin_amdgcn_s_setprio(1);
#pragma unroll
        for (int mi = 0; mi < 4; ++mi)
#pragma unroll
            for (int ni = 0; ni < 4; ++ni)
                acc[mi][ni] = __builtin_amdgcn_mfma_f32_16x16x32_f16(
                    a[mi], b[ni], acc[mi][ni], 0, 0, 0);
        __builtin_amdgcn_s_setprio(0);

        WAIT_LGKM0;
        __builtin_amdgcn_s_barrier();
        if (t + 2 < NT) stage(base, (t + 2) * 32);
    }

#pragma unroll
    for (int mi = 0; mi < 4; ++mi) {
#pragma unroll
        for (int reg = 0; reg < 4; ++reg) {
            int row = brow + wm * 64 + mi * 16 + fs * 4 + reg;
#pragma unroll
            for (int ni = 0; ni < 4; ++ni) {
                int col = bcol + wn * 64 + ni * 16 + fr;
                G16[(size_t)row * N + col] = f2h(acc[mi][ni][reg]);
            }
        }
    }
}

// ---------------------------------------------------------------------------
// Windowed logits reading token FP32 directly: in-kernel fp16 hi/lo split
// (bit-identical to pre-conversion) via reg-staging + ds_write; G via
// global_load_lds (issued FIRST per tile so counted vmcnt covers it under
// any compiler motion of the pure reg loads). BM=64 x BN=64,
// tmap-balanced grid (40,32), 2-deep pipeline, 2 barriers/iter.
// LDS: 2 x 12 KB {TH 4K | TL 4K | G 4K}.
__global__ __launch_bounds__(256) void k_logits_f32(
    const float* __restrict__ tok, const unsigned short* __restrict__ G16,
    const float* __restrict__ cvec, const int* __restrict__ qp,
    const int* __restrict__ tmap, float* __restrict__ logits)
{
    const int d = blockIdx.x + 40 * blockIdx.y;          // 0..1279
    const int logical = (d & 7) * 160 + (d >> 3);        // XCD-chunked bijection
    const int t0   = logical % 40;
    const int brow = (logical / 40) * 64;
    if (t0 >= tmap[40]) return;                          // block-uniform
    const int m    = tmap[t0];
    const int b    = m >> 16;
    const int bcol = m & 0xffff;
    const int start = qp[b];

    __shared__ __align__(16) char lds[2 * 12288];

    const int tid = threadIdx.x;
    const int ln  = tid & 63;
    const int wid = tid >> 6;
    const int fr  = ln & 15, fs = ln >> 4;
    const int srow = tid >> 2;
    const int sslt = tid & 3;

    const int kka = (sslt ^ swz(srow)) << 3;             // element offset
    const size_t tokOff = ((size_t)b * LQ + brow + srow) * D_DIM + kka;
    int wr = start + bcol + srow; if (wr > NQ - 1) wr = NQ - 1;
    const size_t offW0 = (size_t)wr * D_DIM + kka;
    const int ldsByte = srow * 64 + sslt * 16;           // linear dest (matches read swizzle)

    f32x4 acc[4] = {};

    // issue one tile's loads: G FIRST (gload_lds), then token fp32 to regs
    auto issueTile = [&](int k0, char* gdst, float4& x0, float4& x1) {
        gload_lds16(G16 + offW0 + k0, gdst);
        x0 = *reinterpret_cast<const float4*>(tok + tokOff + k0);
        x1 = *reinterpret_cast<const float4*>(tok + tokOff + k0 + 4);
    };
    // convert + write TH/TL into buffer
    auto writeTile = [&](char* base, float4 x0, float4 x1) {
        float xs[8] = {x0.x, x0.y, x0.z, x0.w, x1.x, x1.y, x1.z, x1.w};
        ushort8 h8, l8;
#pragma unroll
        for (int k = 0; k < 8; ++k) {
            unsigned short h = f2h(xs[k]);
            h8[k] = h;
            l8[k] = f2h(xs[k] - h2f(h));
        }
        *reinterpret_cast<ushort8*>(base + ldsByte) = h8;
        *reinterpret_cast<ushort8*>(base + 4096 + ldsByte) = l8;
    };
    auto compute = [&](char* base) {
        half8 ah, al, bf[4];
        {
            int r = wid * 16 + fr;
            int o = r * 64 + ((fs ^ swz(r)) << 4);
            ah = *reinterpret_cast<const half8*>(base + o);
            al = *reinterpret_cast<const half8*>(base + 4096 + o);
        }
#pragma unroll
        for (int ni = 0; ni < 4; ++ni) {
            int cc = ni * 16 + fr;
            bf[ni] = *reinterpret_cast<const half8*>(base + 8192 + cc * 64 + ((fs ^ swz(cc)) << 4));
        }
        __builtin_amdgcn_s_setprio(1);
#pragma unroll
        for (int ni = 0; ni < 4; ++ni)
            acc[ni] = __builtin_amdgcn_mfma_f32_16x16x32_f16(ah, bf[ni], acc[ni], 0, 0, 0);
#pragma unroll
        for (int ni = 0; ni < 4; ++ni)
            acc[ni] = __builtin_amdgcn_mfma_f32_16x16x32_f16(al, bf[ni], acc[ni], 0, 0, 0);
        __builtin_amdgcn_s_setprio(0);
    };

    float4 a0, a1, b0, b1;                       // two in-flight tiles (named: rule #20)
    issueTile(0,  lds + 8192 + wid * 1024, a0, a1);
    issueTile(32, lds + 12288 + 8192 + wid * 1024, b0, b1);

    const int NT = D_DIM / 32;                   // 32 (even)
    for (int tt = 0; tt < NT / 2; ++tt) {
        {   // even tile t = 2*tt, buffer 0
            int t = 2 * tt;
            if (t < NT - 1) { WAIT_VM3; } else { WAIT_VM0; }
            writeTile(lds, a0, a1);
            WAIT_LGKM0;
            __builtin_amdgcn_s_barrier();
            compute(lds);
            __builtin_amdgcn_s_barrier();
            if (t + 2 < NT) issueTile((t + 2) * 32, lds + 8192 + wid * 1024, a0, a1);
        }
        {   // odd tile t = 2*tt+1, buffer 1
            int t = 2 * tt + 1;
            if (t < NT - 1) { WAIT_VM3; } else { WAIT_VM0; }
            writeTile(lds + 12288, b0, b1);
            WAIT_LGKM0;
            __builtin_amdgcn_s_barrier();
            compute(lds + 12288);
            __builtin_amdgcn_s_barrier();
            if (t + 2 < NT) issueTile((t + 2) * 32, lds + 12288 + 8192 + wid * 1024, b0, b1);
        }
    }

    float cv[4];
#pragma unroll
    for (int ni = 0; ni < 4; ++ni) {
        int ci = start + bcol + ni * 16 + fr;
        if (ci > NQ - 1) ci = NQ - 1;
        cv[ni] = cvec[ci];
    }

#pragma unroll
    for (int reg = 0; reg < 4; ++reg) {
        size_t row = (size_t)b * LQ + brow + wid * 16 + fs * 4 + reg;
#pragma unroll
        for (int ni = 0; ni < 4; ++ni) {
            int col = bcol + ni * 16 + fr;
            logits[row * SMAX + col] = acc[ni][reg] + cv[ni];
        }
    }
}

// ---------------------------------------------------------------------------
// Wave-per-row top-8 + softmax + ZW gather + out_b -> final fp32 output.
__global__ __launch_bounds__(256) void k_topk_out(
    const float* __restrict__ logits, const unsigned short* __restrict__ ZW,
    const float* __restrict__ out_b, const int* __restrict__ qp,
    float* __restrict__ out)
{
    const int ln  = threadIdx.x & 63;
    const int row = blockIdx.x * 4 + (threadIdx.x >> 6);   // (b*L + l)
    const int b   = row >> 11;                              // L = 2048
    const int start = qp[b], len = qp[b + 1] - start;

    const float* lrow = logits + (size_t)row * SMAX;

    float v[16];
#pragma unroll
    for (int c = 0; c < 4; ++c) {
        float4 q = reinterpret_cast<const float4*>(lrow)[c * 64 + ln];
        int s0 = c * 256 + ln * 4;
        v[c * 4 + 0] = (s0 + 0 < len) ? q.x : -INFINITY;
        v[c * 4 + 1] = (s0 + 1 < len) ? q.y : -INFINITY;
        v[c * 4 + 2] = (s0 + 2 < len) ? q.z : -INFINITY;
        v[c * 4 + 3] = (s0 + 3 < len) ? q.w : -INFINITY;
    }

    float wv[TOPK]; int wi[TOPK];
#pragma unroll
    for (int it = 0; it < TOPK; ++it) {
        float bvv = v[0]; int bj = 0;
#pragma unroll
        for (int j = 1; j < 16; ++j)
            if (v[j] > bvv) { bvv = v[j]; bj = j; }
        int gidx = (bj >> 2) * 256 + ln * 4 + (bj & 3);
        float cv = bvv; int ci = gidx;
#pragma unroll
        for (int off = 32; off > 0; off >>= 1) {
            float ov = __shfl_xor(cv, off);
            int   oi = __shfl_xor(ci, off);
            if (ov > cv || (ov == cv && oi < ci)) { cv = ov; ci = oi; }
        }
        wv[it] = cv; wi[it] = ci;
#pragma unroll
        for (int j = 0; j < 16; ++j) {
            int sj = (j >> 2) * 256 + ln * 4 + (j & 3);
            if (sj == ci) v[j] = -INFINITY;
        }
    }

    float m = wv[0], denom = 0.f;
    float g[TOPK];
#pragma unroll
    for (int k = 0; k < TOPK; ++k) { g[k] = expf(wv[k] - m); denom += g[k]; }
    float inv = 1.f / denom;

    float4 acc[4];
#pragma unroll
    for (int c = 0; c < 4; ++c)
        acc[c] = reinterpret_cast<const float4*>(out_b)[c * 64 + ln];

#pragma unroll
    for (int k = 0; k < TOPK; ++k) {
        int si = wi[k] >= 0 ? wi[k] : 0;
        const ushort4v* zr = reinterpret_cast<const ushort4v*>(
            ZW + (size_t)(start + si) * D_DIM);
        float wgt = g[k] * inv;
#pragma unroll
        for (int c = 0; c < 4; ++c) {
            ushort4v z = zr[c * 64 + ln];
            acc[c].x = fmaf(wgt, bf2f(z[0]), acc[c].x);
            acc[c].y = fmaf(wgt, bf2f(z[1]), acc[c].y);
            acc[c].z = fmaf(wgt, bf2f(z[2]), acc[c].z);
            acc[c].w = fmaf(wgt, bf2f(z[3]), acc[c].w);
        }
    }
    float* orow = out + (size_t)row * D_DIM;
#pragma unroll
    for (int c = 0; c < 4; ++c)
        reinterpret_cast<float4*>(orow)[c * 64 + ln] = acc[c];
}

// ---------------------------------------------------------------------------
extern "C" void kernel_launch(void* const* d_in, const int* in_sizes, int n_in,
                              void* d_out, int out_size, void* d_ws, size_t ws_size,
                              hipStream_t stream) {
    const float* token_states = (const float*)d_in[0];
    const float* Z_sets       = (const float*)d_in[1];
    const float* desc_q       = (const float*)d_in[2];
    const int*   q_raw        = (const int*)d_in[3];
    const float* Wg_w  = (const float*)d_in[4];
    const float* Wg_b  = (const float*)d_in[5];
    const float* Wd_w  = (const float*)d_in[6];
    const float* Wd_b  = (const float*)d_in[7];
    const float* out_w = (const float*)d_in[8];
    const float* out_b = (const float*)d_in[9];
    float* out = (float*)d_out;

    const size_t NDES = (size_t)NQ * D_DIM;        // 2097152
    const size_t NW   = (size_t)D_DIM * D_DIM;     // 1048576

    char* ws = (char*)d_ws;
    int* qp   = (int*)ws;                                    // [0,64)
    int* tmap = (int*)(ws + 64);                             // [64,256)
    unsigned short* descH   = (unsigned short*)(ws + 256);   // fp16 [2048][1024]
    unsigned short* descL   = descH + NDES;                  // fp16
    unsigned short* wdh     = descL + NDES;                  // fp16
    unsigned short* wgT     = wdh + NW;                      // fp16 (Wg^T)
    unsigned short* owb     = wgT + NW;                      // bf16
    unsigned short* Zb      = owb + NW;                      // bf16
    unsigned short* Dproj16 = Zb + NDES;                     // fp16 [2048][1024]
    unsigned short* ZWb     = Dproj16 + NDES;                // bf16 [2048][1024]
    unsigned short* G16     = ZWb + NDES;                    // fp16 [2048][1024]
    float* cvec             = (float*)(G16 + NDES);          // fp32 [2048]
    float* logit            = cvec + 2048;                   // fp32 [8192][1024]

    // conversions + qptrs + Wg transpose (token not pre-converted)
    k_cvt_all<<<3328, 256, 0, stream>>>(
        desc_q, Wd_w, out_w, Z_sets, Wg_w, q_raw,
        descH, descL, wdh, owb, Zb, wgT, qp);

    // Dproj (2-pass fp16-split) + ZW (bf16): 256 blocks
    k_dzw<<<256, 256, 0, stream>>>(
        descH, descL, wdh, Wd_b, Dproj16, Zb, owb, ZWb);

    // G = Dproj @ Wg + cvec + tmap: 640 blocks co-run
    k_gc<<<640, 256, 0, stream>>>(
        Dproj16, wgT, G16, Wg_b, qp, tmap, cvec);

    // logits = token(fp32, in-kernel split) @ G^T + c: grid (40, 32)
    k_logits_f32<<<dim3(40, 32), 256, 0, stream>>>(
        token_states, G16, cvec, qp, tmap, logit);

    // top-8 + softmax + ZW gather + bias -> final output
    k_topk_out<<<(BQ * LQ) / 4, 256, 0, stream>>>(logit, ZWb, out_b, qp, out);
}